// Round 7
// baseline (423.658 us; speedup 1.0000x reference)
//
#include <hip/hip_runtime.h>

#define B_ 8
#define C_ 64
#define H_ 256
#define W_ 256
#define HW_ 65536
#define PLANE_ 33554432  // B*C*H*W

typedef __attribute__((ext_vector_type(8))) short short8;
typedef __attribute__((ext_vector_type(4))) float f32x4;
typedef __attribute__((ext_vector_type(4))) unsigned short ushort4v;

__device__ __forceinline__ unsigned short f2bf(float f){
  unsigned u = __float_as_uint(f);
  u += 0x7fffu + ((u >> 16) & 1u);
  return (unsigned short)(u >> 16);
}

// ---------------- kernel 1: QKV projection ----------------
// grid = B*H, 256 thr. Block (b,h): Out_p[o][w] = sum_i W_p[o][i]*x[b,i,h,w] + b_p[o]
// A = X^T (rows w), B = W (cols o). Outputs bounced through LDS so global
// stores are 512B-contiguous per wave (fixes 32B-scatter write inefficiency).
// LDS: Xt 32KB (X^T tile, reused as output bounce) + Wl 8KB (one projection's W).
__global__ __launch_bounds__(256, 4) void proj_kernel(
    const float* __restrict__ x,
    const float* __restrict__ Wq, const float* __restrict__ bq,
    const float* __restrict__ Wk, const float* __restrict__ bk,
    const float* __restrict__ Wv, const float* __restrict__ bv,
    unsigned short* __restrict__ Qb, unsigned short* __restrict__ Kb,
    unsigned short* __restrict__ Vb)
{
  __shared__ unsigned short lds[W_*64 + 64*64];   // 32KB Xt/Obuf + 8KB Wl
  unsigned short* Xt = lds;
  unsigned short* Wl = lds + W_*64;
  const int tid = threadIdx.x;
  const int lane = tid & 63;
  const int wv  = tid >> 6;
  const int q4 = lane >> 4, l16 = lane & 15;
  const int bid = blockIdx.x;
  const int b = bid >> 8, h = bid & 255;

  const float* wsrc[3] = {Wq, Wk, Wv};
  const float* bsrc[3] = {bq, bk, bv};

  // ---- phase A: issue ALL long-latency loads first (16 float4 x + 4 float4 W0) ----
  const float* xb = x + (size_t)b*C_*HW_ + (size_t)h*W_;
  float4 xv[16];
  #pragma unroll
  for (int it=0; it<16; ++it){
    int i = it*4 + wv;
    xv[it] = *(const float4*)(xb + (size_t)i*HW_ + lane*4);
  }
  float4 w0v[4];
  #pragma unroll
  for (int k=0;k<4;++k){
    int idx4 = k*256 + tid;               // 1024 float4 = W of projection 0
    int o = idx4 >> 4, i4 = idx4 & 15;
    w0v[k] = *(const float4*)(Wq + o*64 + i4*4);
  }
  float biasr[3][4];
  #pragma unroll
  for (int p=0;p<3;++p)
    #pragma unroll
    for (int nf=0;nf<4;++nf)
      biasr[p][nf] = bsrc[p][nf*16 + l16];

  // convert + write X^T [w][i] bf16 (xor-swizzled)
  #pragma unroll
  for (int it=0; it<16; ++it){
    int i = it*4 + wv;
    float fv[4] = {xv[it].x, xv[it].y, xv[it].z, xv[it].w};
    #pragma unroll
    for (int k2=0;k2<4;++k2){
      int w = lane*4 + k2;
      int slot = (w&7) ^ ((w>>3)&7);
      Xt[w*64 + (i ^ (slot<<3))] = f2bf(fv[k2]);
    }
  }
  // write W0 (bf16, swizzled [o][i^key], key=(o&7)<<3)
  #pragma unroll
  for (int k=0;k<4;++k){
    int idx4 = k*256 + tid;
    int o = idx4 >> 4, i4 = idx4 & 15;
    ushort4v sv;
    sv[0]=f2bf(w0v[k].x); sv[1]=f2bf(w0v[k].y); sv[2]=f2bf(w0v[k].z); sv[3]=f2bf(w0v[k].w);
    *(ushort4v*)&Wl[o*64 + ((i4*4) ^ ((o&7)<<3))] = sv;
  }
  __syncthreads();

  // A-frags (X^T rows w); Xt dead afterwards -> reused as output bounce buffer
  short8 aX[4][2];
  #pragma unroll
  for (int mf=0;mf<4;++mf){
    int w = wv*64 + mf*16 + l16;
    int slot = (w&7) ^ ((w>>3)&7);
    #pragma unroll
    for (int kk=0;kk<2;++kk)
      aX[mf][kk] = *(const short8*)&Xt[w*64 + ((8*q4 + 32*kk) ^ (slot<<3))];
  }

  unsigned short* outp[3] = {Qb, Kb, Vb};
  const size_t obase = (size_t)b*C_*HW_ + (size_t)h*W_;
  unsigned short* Obuf = Xt;   // [o][w4 swizzled], 64 x 256 bf16

  #pragma unroll
  for (int p=0;p<3;++p){
    // compute, convert to packed bf16 per nf (keeps VGPR low)
    ushort4v pk[4][4];
    #pragma unroll
    for (int nf=0;nf<4;++nf){
      const int o = nf*16 + l16;
      const int key = (o&7)<<3;
      short8 bW0 = *(const short8*)&Wl[o*64 + ((8*q4)      ^ key)];
      short8 bW1 = *(const short8*)&Wl[o*64 + ((8*q4 + 32) ^ key)];
      f32x4 acc[4];
      #pragma unroll
      for (int mf=0;mf<4;++mf){ f32x4 z={0.f,0.f,0.f,0.f}; acc[mf]=z; }
      #pragma unroll
      for (int mf=0;mf<4;++mf)
        acc[mf] = __builtin_amdgcn_mfma_f32_16x16x32_bf16(aX[mf][0], bW0, acc[mf], 0,0,0);
      #pragma unroll
      for (int mf=0;mf<4;++mf)
        acc[mf] = __builtin_amdgcn_mfma_f32_16x16x32_bf16(aX[mf][1], bW1, acc[mf], 0,0,0);
      const float bb = biasr[p][nf];
      #pragma unroll
      for (int mf=0;mf<4;++mf){
        ushort4v sv;
        #pragma unroll
        for (int r=0;r<4;++r) sv[r] = f2bf(acc[mf][r] + bb);
        pk[nf][mf] = sv;
      }
    }
    // prefetch next projection's W (global loads issued before barrier)
    float4 wnv[4];
    if (p < 2){
      #pragma unroll
      for (int k=0;k<4;++k){
        int idx4 = k*256 + tid;
        int o = idx4 >> 4, i4 = idx4 & 15;
        wnv[k] = *(const float4*)(wsrc[p+1] + o*64 + i4*4);
      }
    }
    __syncthreads();   // all waves done reading Wl_p; Obuf free (prev store done)

    // bounce acc -> Obuf [o][w4 ^ (o&7)<<3], 8B units; <=2-way conflicts
    #pragma unroll
    for (int nf=0;nf<4;++nf){
      const int o = nf*16 + l16;
      const int key = (o&7)<<3;
      #pragma unroll
      for (int mf=0;mf<4;++mf){
        int w4 = wv*16 + mf*4 + q4;
        *(ushort4v*)&Obuf[o*256 + ((w4 ^ key)<<2)] = pk[nf][mf];
      }
    }
    if (p < 2){
      #pragma unroll
      for (int k=0;k<4;++k){
        int idx4 = k*256 + tid;
        int o = idx4 >> 4, i4 = idx4 & 15;
        ushort4v sv;
        sv[0]=f2bf(wnv[k].x); sv[1]=f2bf(wnv[k].y); sv[2]=f2bf(wnv[k].z); sv[3]=f2bf(wnv[k].w);
        *(ushort4v*)&Wl[o*64 + ((i4*4) ^ ((o&7)<<3))] = sv;
      }
    }
    __syncthreads();

    // coalesced store: wave wv handles rows o = wv*16 .. wv*16+15; 512B per instr
    unsigned short* op = outp[p];
    #pragma unroll
    for (int rr=0; rr<16; ++rr){
      const int o = wv*16 + rr;
      const int key = (o&7)<<3;
      ushort4v sv = *(const ushort4v*)&Obuf[o*256 + ((lane ^ key)<<2)];
      *(ushort4v*)&op[obase + (size_t)o*HW_ + lane*4] = sv;
    }
  }
}

// ---------------- kernel 2: in-place V transpose (per (b,c) 256x256) ----------------
__global__ __launch_bounds__(256) void transpose_v(unsigned short* __restrict__ Vb)
{
  const int pi[10] = {0,0,0,0,1,1,1,2,2,3};
  const int pj[10] = {0,1,2,3,1,2,3,2,3,3};
  __shared__ unsigned short tA[64*72];
  __shared__ unsigned short tB[64*72];
  int t = threadIdx.x;
  int bid = blockIdx.x;
  int bc = bid / 10, pr = bid - bc*10;
  int ti = pi[pr], tj = pj[pr];
  unsigned short* base = Vb + (size_t)bc*HW_;
  int diag = (ti == tj);
  #pragma unroll
  for (int k=0;k<2;++k){
    int flat = t + k*256;
    int i = flat >> 3, j = (flat & 7)*8;
    int4 va = *(const int4*)(base + (size_t)(ti*64+i)*256 + tj*64 + j);
    *(int4*)&tA[i*72 + j] = va;
    if (!diag){
      int4 vb2 = *(const int4*)(base + (size_t)(tj*64+i)*256 + ti*64 + j);
      *(int4*)&tB[i*72 + j] = vb2;
    }
  }
  __syncthreads();
  #pragma unroll
  for (int k=0;k<2;++k){
    int flat = t + k*256;
    int i = flat >> 3, j = (flat & 7)*8;
    int4 vo; unsigned short* po = (unsigned short*)&vo;
    #pragma unroll
    for (int e=0;e<8;++e) po[e] = tA[(j+e)*72 + i];
    *(int4*)(base + (size_t)(tj*64+i)*256 + ti*64 + j) = vo;
    if (!diag){
      int4 vo2; unsigned short* po2 = (unsigned short*)&vo2;
      #pragma unroll
      for (int e=0;e<8;++e) po2[e] = tB[(j+e)*72 + i];
      *(int4*)(base + (size_t)(ti*64+i)*256 + tj*64 + j) = vo2;
    }
  }
}

// ---------------- kernel 3: attention + BN + PReLU ----------------
// Row swizzle key over the full 32-int4-slot row: spreads frag reads across banks.
__device__ __forceinline__ int swzkey(int r){ return (r & 31) ^ ((r & 3) << 3); }

// async global->LDS: linear LDS dest, inverse-swizzled global source (involution).
__device__ __forceinline__ void stage_tile(unsigned short* dst, const unsigned short* src, int tid){
  #pragma unroll
  for (int k=0;k<8;++k){
    int j = tid + k*256;                 // int4 slot
    int gj = j ^ swzkey(j >> 5);         // row = j>>5 (32 int4 per 256-ushort row)
    __builtin_amdgcn_global_load_lds(
      (const __attribute__((address_space(1))) void*)(src + (size_t)gj*8),
      (__attribute__((address_space(3))) void*)(dst + (size_t)j*8),
      16, 0, 0);
  }
}

__global__ __launch_bounds__(256) void attn_kernel(
    const unsigned short* __restrict__ Qb, const unsigned short* __restrict__ Kb,
    const unsigned short* __restrict__ Vtb,
    const float* __restrict__ gamma, const float* __restrict__ beta,
    const float* __restrict__ rmean, const float* __restrict__ rvar,
    const float* __restrict__ alphaP,
    float* __restrict__ out)
{
  __shared__ unsigned short s[64*256];   // single 32 KB buffer: K tiles -> P -> V tiles
  const int tid = threadIdx.x;
  const int lane = tid & 63;
  const int wv = tid >> 6;
  const int q4 = lane >> 4, l16 = lane & 15;
  // XCD-bijective remap: 4 h-tiles of each (b,c) contiguous on one XCD
  const int n = blockIdx.x;
  const int work = (n & 7)*256 + (n >> 3);
  const int bc = work >> 2, ht = work & 3;
  const int c = bc & 63;

  const unsigned short* Qp = Qb  + (size_t)bc*HW_ + (size_t)ht*64*W_;
  const unsigned short* Kp = Kb  + (size_t)bc*HW_;
  const unsigned short* Vp = Vtb + (size_t)bc*HW_;

  stage_tile(s, Kp, tid);

  // Q fragments direct from global (no reuse -> no staging)
  short8 aq[8];
  {
    const int row = wv*16 + l16;
    #pragma unroll
    for (int kk=0;kk<8;++kk)
      aq[kk] = *(const short8*)(Qp + (size_t)row*W_ + 8*q4 + 32*kk);
  }

  f32x4 sa[16];
  #pragma unroll
  for (int f=0;f<16;++f){ f32x4 z={0.f,0.f,0.f,0.f}; sa[f]=z; }

  __syncthreads();
  #pragma unroll
  for (int gt=0; gt<4; ++gt){
    #pragma unroll
    for (int nf=0;nf<4;++nf){
      const int g = nf*16 + l16;
      const int ko = swzkey(g);
      const int f = gt*4 + nf;
      #pragma unroll
      for (int kk=0;kk<8;++kk){
        short8 bk_ = *(const short8*)&s[g*256 + (((q4 + 4*kk) ^ ko) << 3)];
        sa[f] = __builtin_amdgcn_mfma_f32_16x16x32_bf16(aq[kk], bk_, sa[f], 0,0,0);
      }
    }
    __syncthreads();
    if (gt < 3){
      stage_tile(s, Kp + (size_t)(gt+1)*64*W_, tid);
      __syncthreads();
    }
  }

  // wave-local softmax; rows h_local = 4*q4 + r, cols g = 16*f + l16
  float mrow[4], rden[4];
  #pragma unroll
  for (int r=0;r<4;++r){
    float m = -3.0e38f;
    #pragma unroll
    for (int f=0;f<16;++f) m = fmaxf(m, sa[f][r]);
    m = fmaxf(m, __shfl_xor(m, 1, 16));
    m = fmaxf(m, __shfl_xor(m, 2, 16));
    m = fmaxf(m, __shfl_xor(m, 4, 16));
    m = fmaxf(m, __shfl_xor(m, 8, 16));
    mrow[r] = m;
  }
  const float cs = 0.25f * 1.4426950408889634f;  // /H^0.25 folded, exp->exp2
  float psum[4] = {0.f,0.f,0.f,0.f};
  #pragma unroll
  for (int f=0;f<16;++f){
    #pragma unroll
    for (int r=0;r<4;++r){
      float pv = exp2f((sa[f][r] - mrow[r]) * cs);
      sa[f][r] = pv;
      psum[r] += pv;
    }
  }
  #pragma unroll
  for (int r=0;r<4;++r){
    float ssum = psum[r];
    ssum += __shfl_xor(ssum, 1, 16);
    ssum += __shfl_xor(ssum, 2, 16);
    ssum += __shfl_xor(ssum, 4, 16);
    ssum += __shfl_xor(ssum, 8, 16);
    rden[r] = 1.0f / ssum;
  }

  // normalized P (bf16) -> s (denominator folded in here)
  #pragma unroll
  for (int r=0;r<4;++r){
    const int row = wv*16 + 4*q4 + r;
    const int ko = swzkey(row);
    #pragma unroll
    for (int f=0;f<16;++f){
      const int g2 = l16 + 16*f;
      s[row*256 + ((((g2>>3) ^ ko) << 3) | (g2 & 7))] = f2bf(sa[f][r] * rden[r]);
    }
  }
  __syncthreads();

  // P as B-operand fragments (cols = this wave's 16 h rows)
  short8 pb[8];
  {
    const int row = wv*16 + l16;
    const int ko = swzkey(row);
    #pragma unroll
    for (int kk=0;kk<8;++kk)
      pb[kk] = *(const short8*)&s[row*256 + (((q4 + 4*kk) ^ ko) << 3)];
  }
  __syncthreads();

  f32x4 oa[16];
  #pragma unroll
  for (int f=0;f<16;++f){ f32x4 z={0.f,0.f,0.f,0.f}; oa[f]=z; }

  stage_tile(s, Vp, tid);
  __syncthreads();
  #pragma unroll
  for (int wt=0; wt<4; ++wt){
    #pragma unroll
    for (int nf=0;nf<4;++nf){
      const int wrow = nf*16 + l16;     // tile-local Vt row (= output col w)
      const int ko = swzkey(wrow);
      const int mw = wt*4 + nf;
      #pragma unroll
      for (int kk=0;kk<8;++kk){
        short8 av = *(const short8*)&s[wrow*256 + (((q4 + 4*kk) ^ ko) << 3)];
        oa[mw] = __builtin_amdgcn_mfma_f32_16x16x32_bf16(av, pb[kk], oa[mw], 0,0,0);
      }
    }
    __syncthreads();
    if (wt < 3){
      stage_tile(s, Vp + (size_t)(wt+1)*64*W_, tid);
      __syncthreads();
    }
  }

  // epilogue: BatchNorm(eval) + PReLU, packed float4 stores (D rows = w, cols = h)
  const float inv   = gamma[c] / sqrtf(rvar[c] + 1e-5f);
  const float shift = beta[c] - rmean[c]*inv;
  const float al    = alphaP[0];
  float* ob = out + (size_t)bc*HW_ + (size_t)ht*64*W_;
  const int hrow = wv*16 + l16;
  #pragma unroll
  for (int mw=0; mw<16; ++mw){
    f32x4 v;
    #pragma unroll
    for (int r=0;r<4;++r){
      float t = oa[mw][r]*inv + shift;
      v[r] = (t >= 0.f) ? t : al*t;
    }
    *(f32x4*)&ob[(size_t)hrow*W_ + mw*16 + 4*q4] = v;
  }
}

extern "C" void kernel_launch(void* const* d_in, const int* in_sizes, int n_in,
                              void* d_out, int out_size, void* d_ws, size_t ws_size,
                              hipStream_t stream)
{
  const float* x     = (const float*)d_in[0];
  const float* Wq    = (const float*)d_in[1];
  const float* bq    = (const float*)d_in[2];
  const float* Wk    = (const float*)d_in[3];
  const float* bk    = (const float*)d_in[4];
  const float* Wv    = (const float*)d_in[5];
  const float* bv    = (const float*)d_in[6];
  const float* gamma = (const float*)d_in[7];
  const float* beta  = (const float*)d_in[8];
  const float* rmean = (const float*)d_in[9];
  const float* rvar  = (const float*)d_in[10];
  const float* alpha = (const float*)d_in[11];
  float* out = (float*)d_out;

  unsigned short* Qb = (unsigned short*)d_ws;          // 64 MB bf16
  unsigned short* Kb = Qb + (size_t)PLANE_;            // 64 MB bf16
  unsigned short* Vb = Kb + (size_t)PLANE_;            // 64 MB bf16 (becomes V^T)

  proj_kernel<<<B_*H_, 256, 0, stream>>>(x, Wq,bq, Wk,bk, Wv,bv, Qb, Kb, Vb);
  transpose_v<<<B_*C_*10, 256, 0, stream>>>(Vb);
  attn_kernel<<<B_*C_*4, 256, 0, stream>>>(Qb, Kb, Vb, gamma, beta, rmean, rvar, alpha, out);
}

// Round 10
// 409.122 us; speedup vs baseline: 1.0355x; 1.0355x over previous
//
#include <hip/hip_runtime.h>

#define B_ 8
#define C_ 64
#define H_ 256
#define W_ 256
#define HW_ 65536
#define PLANE_ 33554432  // B*C*H*W

typedef __attribute__((ext_vector_type(8))) short short8;
typedef __attribute__((ext_vector_type(4))) float f32x4;
typedef __attribute__((ext_vector_type(4))) unsigned short ushort4v;

__device__ __forceinline__ unsigned short f2bf(float f){
  unsigned u = __float_as_uint(f);
  u += 0x7fffu + ((u >> 16) & 1u);
  return (unsigned short)(u >> 16);
}

// ---------------- kernel 1: QKV projection ----------------
// grid = B*H, 256 thr. Block (b,h): Out_p[o][w] = sum_i W_p[o][i]*x[b,i,h,w] + b_p[o]
// x staged as FP32 via global_load_lds DMA (no VGPR latency chain); A-frags built
// by LDS read+convert. W in 8KB LDS pane, re-staged per projection w/ prefetch.
// Stores: direct scattered 8B (L2 write-combines to 192MB ideal — measured r6).
__global__ __launch_bounds__(256, 2) void proj_kernel(
    const float* __restrict__ x,
    const float* __restrict__ Wq, const float* __restrict__ bq,
    const float* __restrict__ Wk, const float* __restrict__ bk,
    const float* __restrict__ Wv, const float* __restrict__ bv,
    unsigned short* __restrict__ Qb, unsigned short* __restrict__ Kb,
    unsigned short* __restrict__ Vb)
{
  __shared__ float Xf[64*256];              // 64 KB: x tile fp32 [i][w]
  __shared__ unsigned short Wl[64*64];      // 8 KB: one projection's W bf16
  const int tid = threadIdx.x;
  const int lane = tid & 63;
  const int wv  = tid >> 6;
  const int q4 = lane >> 4, l16 = lane & 15;
  const int bid = blockIdx.x;
  const int b = bid >> 8, h = bid & 255;

  const float* wsrc[3] = {Wq, Wk, Wv};
  const float* bsrc[3] = {bq, bk, bv};
  const float* xb = x + (size_t)b*C_*HW_ + (size_t)h*W_;

  // ---- issue all 16 x-DMA loads first (async, no VGPR round-trip) ----
  #pragma unroll
  for (int k=0;k<16;++k){
    int f = k*256 + tid;          // 16B chunk id, 0..4095
    int i = f >> 6;               // row (1KB = 64 chunks)
    int c = f & 63;
    __builtin_amdgcn_global_load_lds(
      (const __attribute__((address_space(1))) void*)(xb + (size_t)i*HW_ + c*4),
      (__attribute__((address_space(3))) void*)(Xf + (size_t)f*4),
      16, 0, 0);
  }

  // W0 load + biases while DMA streams
  float4 w0v[4];
  #pragma unroll
  for (int k=0;k<4;++k){
    int idx4 = k*256 + tid;               // 1024 float4 = one W
    int o = idx4 >> 4, i4 = idx4 & 15;
    w0v[k] = *(const float4*)(Wq + o*64 + i4*4);
  }
  float biasr[3][4];
  #pragma unroll
  for (int p=0;p<3;++p)
    #pragma unroll
    for (int nf=0;nf<4;++nf)
      biasr[p][nf] = bsrc[p][nf*16 + l16];

  // write W0 (bf16, swizzled [o][i^key], key=(o&7)<<3)
  #pragma unroll
  for (int k=0;k<4;++k){
    int idx4 = k*256 + tid;
    int o = idx4 >> 4, i4 = idx4 & 15;
    ushort4v sv;
    sv[0]=f2bf(w0v[k].x); sv[1]=f2bf(w0v[k].y); sv[2]=f2bf(w0v[k].z); sv[3]=f2bf(w0v[k].w);
    *(ushort4v*)&Wl[o*64 + ((i4*4) ^ ((o&7)<<3))] = sv;
  }
  __syncthreads();   // drains x DMA + W0 writes

  // ---- build A-frags from Xf (fp32 LDS -> bf16 regs) ----
  short8 aX[4][2];
  #pragma unroll
  for (int mf=0;mf<4;++mf){
    const int w = wv*64 + mf*16 + l16;
    #pragma unroll
    for (int kk=0;kk<2;++kk){
      const int i0 = 8*q4 + 32*kk;
      short8 t;
      #pragma unroll
      for (int e=0;e<8;++e)
        t[e] = (short)f2bf(Xf[(i0+e)*256 + w]);
      aX[mf][kk] = t;
    }
  }

  unsigned short* outp[3] = {Qb, Kb, Vb};
  const size_t obase = (size_t)b*C_*HW_ + (size_t)h*W_;

  #pragma unroll
  for (int p=0;p<3;++p){
    unsigned short* op = outp[p];
    // prefetch next projection's W early (hidden under compute+stores)
    float4 wnv[4];
    if (p < 2){
      #pragma unroll
      for (int k=0;k<4;++k){
        int idx4 = k*256 + tid;
        int o = idx4 >> 4, i4 = idx4 & 15;
        wnv[k] = *(const float4*)(wsrc[p+1] + o*64 + i4*4);
      }
    }
    #pragma unroll
    for (int nf=0;nf<4;++nf){
      const int o = nf*16 + l16;
      const int key = (o&7)<<3;
      short8 bW0 = *(const short8*)&Wl[o*64 + ((8*q4)      ^ key)];
      short8 bW1 = *(const short8*)&Wl[o*64 + ((8*q4 + 32) ^ key)];
      f32x4 acc[4];
      #pragma unroll
      for (int mf=0;mf<4;++mf){ f32x4 z={0.f,0.f,0.f,0.f}; acc[mf]=z; }
      #pragma unroll
      for (int mf=0;mf<4;++mf)
        acc[mf] = __builtin_amdgcn_mfma_f32_16x16x32_bf16(aX[mf][0], bW0, acc[mf], 0,0,0);
      #pragma unroll
      for (int mf=0;mf<4;++mf)
        acc[mf] = __builtin_amdgcn_mfma_f32_16x16x32_bf16(aX[mf][1], bW1, acc[mf], 0,0,0);
      const float bb = biasr[p][nf];
      #pragma unroll
      for (int mf=0;mf<4;++mf){
        ushort4v sv;
        #pragma unroll
        for (int r=0;r<4;++r) sv[r] = f2bf(acc[mf][r] + bb);
        *(ushort4v*)&op[obase + (size_t)o*HW_ + (wv*64 + mf*16 + 4*q4)] = sv;
      }
    }
    if (p < 2){
      __syncthreads();   // everyone done reading Wl for p
      #pragma unroll
      for (int k=0;k<4;++k){
        int idx4 = k*256 + tid;
        int o = idx4 >> 4, i4 = idx4 & 15;
        ushort4v sv;
        sv[0]=f2bf(wnv[k].x); sv[1]=f2bf(wnv[k].y); sv[2]=f2bf(wnv[k].z); sv[3]=f2bf(wnv[k].w);
        *(ushort4v*)&Wl[o*64 + ((i4*4) ^ ((o&7)<<3))] = sv;
      }
      __syncthreads();
    }
  }
}

// ---------------- kernel 2: in-place V transpose (per (b,c) 256x256) ----------------
__global__ __launch_bounds__(256) void transpose_v(unsigned short* __restrict__ Vb)
{
  const int pi[10] = {0,0,0,0,1,1,1,2,2,3};
  const int pj[10] = {0,1,2,3,1,2,3,2,3,3};
  __shared__ unsigned short tA[64*72];
  __shared__ unsigned short tB[64*72];
  int t = threadIdx.x;
  int bid = blockIdx.x;
  int bc = bid / 10, pr = bid - bc*10;
  int ti = pi[pr], tj = pj[pr];
  unsigned short* base = Vb + (size_t)bc*HW_;
  int diag = (ti == tj);
  #pragma unroll
  for (int k=0;k<2;++k){
    int flat = t + k*256;
    int i = flat >> 3, j = (flat & 7)*8;
    int4 va = *(const int4*)(base + (size_t)(ti*64+i)*256 + tj*64 + j);
    *(int4*)&tA[i*72 + j] = va;
    if (!diag){
      int4 vb2 = *(const int4*)(base + (size_t)(tj*64+i)*256 + ti*64 + j);
      *(int4*)&tB[i*72 + j] = vb2;
    }
  }
  __syncthreads();
  #pragma unroll
  for (int k=0;k<2;++k){
    int flat = t + k*256;
    int i = flat >> 3, j = (flat & 7)*8;
    int4 vo; unsigned short* po = (unsigned short*)&vo;
    #pragma unroll
    for (int e=0;e<8;++e) po[e] = tA[(j+e)*72 + i];
    *(int4*)(base + (size_t)(tj*64+i)*256 + ti*64 + j) = vo;
    if (!diag){
      int4 vo2; unsigned short* po2 = (unsigned short*)&vo2;
      #pragma unroll
      for (int e=0;e<8;++e) po2[e] = tB[(j+e)*72 + i];
      *(int4*)(base + (size_t)(ti*64+i)*256 + tj*64 + j) = vo2;
    }
  }
}

// ---------------- kernel 3: attention + BN + PReLU ----------------
// Row swizzle key over the full 32-int4-slot row: spreads frag reads across banks.
__device__ __forceinline__ int swzkey(int r){ return (r & 31) ^ ((r & 3) << 3); }

// async global->LDS: linear LDS dest, inverse-swizzled global source (involution).
__device__ __forceinline__ void stage_tile(unsigned short* dst, const unsigned short* src, int tid){
  #pragma unroll
  for (int k=0;k<8;++k){
    int j = tid + k*256;                 // int4 slot
    int gj = j ^ swzkey(j >> 5);         // row = j>>5 (32 int4 per 256-ushort row)
    __builtin_amdgcn_global_load_lds(
      (const __attribute__((address_space(1))) void*)(src + (size_t)gj*8),
      (__attribute__((address_space(3))) void*)(dst + (size_t)j*8),
      16, 0, 0);
  }
}

__global__ __launch_bounds__(256) void attn_kernel(
    const unsigned short* __restrict__ Qb, const unsigned short* __restrict__ Kb,
    const unsigned short* __restrict__ Vtb,
    const float* __restrict__ gamma, const float* __restrict__ beta,
    const float* __restrict__ rmean, const float* __restrict__ rvar,
    const float* __restrict__ alphaP,
    float* __restrict__ out)
{
  __shared__ unsigned short s[64*256];   // single 32 KB buffer: K tiles -> P -> V tiles
  const int tid = threadIdx.x;
  const int lane = tid & 63;
  const int wv = tid >> 6;
  const int q4 = lane >> 4, l16 = lane & 15;
  // XCD-bijective remap: 4 h-tiles of each (b,c) contiguous on one XCD
  const int n = blockIdx.x;
  const int work = (n & 7)*256 + (n >> 3);
  const int bc = work >> 2, ht = work & 3;
  const int c = bc & 63;

  const unsigned short* Qp = Qb  + (size_t)bc*HW_ + (size_t)ht*64*W_;
  const unsigned short* Kp = Kb  + (size_t)bc*HW_;
  const unsigned short* Vp = Vtb + (size_t)bc*HW_;

  stage_tile(s, Kp, tid);

  // Q fragments direct from global (no reuse -> no staging)
  short8 aq[8];
  {
    const int row = wv*16 + l16;
    #pragma unroll
    for (int kk=0;kk<8;++kk)
      aq[kk] = *(const short8*)(Qp + (size_t)row*W_ + 8*q4 + 32*kk);
  }

  f32x4 sa[16];
  #pragma unroll
  for (int f=0;f<16;++f){ f32x4 z={0.f,0.f,0.f,0.f}; sa[f]=z; }

  __syncthreads();
  #pragma unroll
  for (int gt=0; gt<4; ++gt){
    #pragma unroll
    for (int nf=0;nf<4;++nf){
      const int g = nf*16 + l16;
      const int ko = swzkey(g);
      const int f = gt*4 + nf;
      #pragma unroll
      for (int kk=0;kk<8;++kk){
        short8 bk_ = *(const short8*)&s[g*256 + (((q4 + 4*kk) ^ ko) << 3)];
        sa[f] = __builtin_amdgcn_mfma_f32_16x16x32_bf16(aq[kk], bk_, sa[f], 0,0,0);
      }
    }
    __syncthreads();
    if (gt < 3){
      stage_tile(s, Kp + (size_t)(gt+1)*64*W_, tid);
      __syncthreads();
    }
  }

  // wave-local softmax; rows h_local = 4*q4 + r, cols g = 16*f + l16
  float mrow[4], rden[4];
  #pragma unroll
  for (int r=0;r<4;++r){
    float m = -3.0e38f;
    #pragma unroll
    for (int f=0;f<16;++f) m = fmaxf(m, sa[f][r]);
    m = fmaxf(m, __shfl_xor(m, 1, 16));
    m = fmaxf(m, __shfl_xor(m, 2, 16));
    m = fmaxf(m, __shfl_xor(m, 4, 16));
    m = fmaxf(m, __shfl_xor(m, 8, 16));
    mrow[r] = m;
  }
  const float cs = 0.25f * 1.4426950408889634f;  // /H^0.25 folded, exp->exp2
  float psum[4] = {0.f,0.f,0.f,0.f};
  #pragma unroll
  for (int f=0;f<16;++f){
    #pragma unroll
    for (int r=0;r<4;++r){
      float pv = exp2f((sa[f][r] - mrow[r]) * cs);
      sa[f][r] = pv;
      psum[r] += pv;
    }
  }
  #pragma unroll
  for (int r=0;r<4;++r){
    float ssum = psum[r];
    ssum += __shfl_xor(ssum, 1, 16);
    ssum += __shfl_xor(ssum, 2, 16);
    ssum += __shfl_xor(ssum, 4, 16);
    ssum += __shfl_xor(ssum, 8, 16);
    rden[r] = 1.0f / ssum;
  }

  // normalized P (bf16) -> s (denominator folded in here)
  #pragma unroll
  for (int r=0;r<4;++r){
    const int row = wv*16 + 4*q4 + r;
    const int ko = swzkey(row);
    #pragma unroll
    for (int f=0;f<16;++f){
      const int g2 = l16 + 16*f;
      s[row*256 + ((((g2>>3) ^ ko) << 3) | (g2 & 7))] = f2bf(sa[f][r] * rden[r]);
    }
  }
  __syncthreads();

  // P as B-operand fragments (cols = this wave's 16 h rows)
  short8 pb[8];
  {
    const int row = wv*16 + l16;
    const int ko = swzkey(row);
    #pragma unroll
    for (int kk=0;kk<8;++kk)
      pb[kk] = *(const short8*)&s[row*256 + (((q4 + 4*kk) ^ ko) << 3)];
  }
  __syncthreads();

  f32x4 oa[16];
  #pragma unroll
  for (int f=0;f<16;++f){ f32x4 z={0.f,0.f,0.f,0.f}; oa[f]=z; }

  stage_tile(s, Vp, tid);
  __syncthreads();
  #pragma unroll
  for (int wt=0; wt<4; ++wt){
    #pragma unroll
    for (int nf=0;nf<4;++nf){
      const int wrow = nf*16 + l16;     // tile-local Vt row (= output col w)
      const int ko = swzkey(wrow);
      const int mw = wt*4 + nf;
      #pragma unroll
      for (int kk=0;kk<8;++kk){
        short8 av = *(const short8*)&s[wrow*256 + (((q4 + 4*kk) ^ ko) << 3)];
        oa[mw] = __builtin_amdgcn_mfma_f32_16x16x32_bf16(av, pb[kk], oa[mw], 0,0,0);
      }
    }
    __syncthreads();
    if (wt < 3){
      stage_tile(s, Vp + (size_t)(wt+1)*64*W_, tid);
      __syncthreads();
    }
  }

  // epilogue: BatchNorm(eval) + PReLU, packed float4 stores (D rows = w, cols = h)
  const float inv   = gamma[c] / sqrtf(rvar[c] + 1e-5f);
  const float shift = beta[c] - rmean[c]*inv;
  const float al    = alphaP[0];
  float* ob = out + (size_t)bc*HW_ + (size_t)ht*64*W_;
  const int hrow = wv*16 + l16;
  #pragma unroll
  for (int mw=0; mw<16; ++mw){
    f32x4 v;
    #pragma unroll
    for (int r=0;r<4;++r){
      float t = oa[mw][r]*inv + shift;
      v[r] = (t >= 0.f) ? t : al*t;
    }
    *(f32x4*)&ob[(size_t)hrow*W_ + mw*16 + 4*q4] = v;
  }
}

extern "C" void kernel_launch(void* const* d_in, const int* in_sizes, int n_in,
                              void* d_out, int out_size, void* d_ws, size_t ws_size,
                              hipStream_t stream)
{
  const float* x     = (const float*)d_in[0];
  const float* Wq    = (const float*)d_in[1];
  const float* bq    = (const float*)d_in[2];
  const float* Wk    = (const float*)d_in[3];
  const float* bk    = (const float*)d_in[4];
  const float* Wv    = (const float*)d_in[5];
  const float* bv    = (const float*)d_in[6];
  const float* gamma = (const float*)d_in[7];
  const float* beta  = (const float*)d_in[8];
  const float* rmean = (const float*)d_in[9];
  const float* rvar  = (const float*)d_in[10];
  const float* alpha = (const float*)d_in[11];
  float* out = (float*)d_out;

  unsigned short* Qb = (unsigned short*)d_ws;          // 64 MB bf16
  unsigned short* Kb = Qb + (size_t)PLANE_;            // 64 MB bf16
  unsigned short* Vb = Kb + (size_t)PLANE_;            // 64 MB bf16 (becomes V^T)

  proj_kernel<<<B_*H_, 256, 0, stream>>>(x, Wq,bq, Wk,bk, Wv,bv, Qb, Kb, Vb);
  transpose_v<<<B_*C_*10, 256, 0, stream>>>(Vb);
  attn_kernel<<<B_*C_*4, 256, 0, stream>>>(Qb, Kb, Vb, gamma, beta, rmean, rvar, alpha, out);
}